// Round 9
// baseline (621.023 us; speedup 1.0000x reference)
//
#include <hip/hip_runtime.h>
#include <math.h>

// Problem constants (shapes fixed by the reference).
constexpr int BN   = 16;        // batch
constexpr int NTOK = 2304;      // tokens
constexpr int DDIM = 1024;      // token dim
constexpr int HH   = 1344;
constexpr int WWp  = 1344;
constexpr int HWPIX = HH * WWp; // 1806336
constexpr int NM   = 8;         // masks
constexpr int HVIS = 48;
constexpr int PATCH = 28;       // 1344/48
constexpr int NRAY = 24;
constexpr int NSMP = 20;
constexpr int NPROB = HVIS * HVIS; // 2304 patches (== NTOK coincidentally)

// ---------------------------------------------------------------------------
// K1: pack 8 int32 mask planes into one byte per pixel (bit m = mask m).
// Loads pinned via sched_barrier so all 8 int4 loads are in flight at once.
// Also zero-inits cnt/sumd/sumd2 (block 0) to save memset dispatches.
__global__ __launch_bounds__(256, 4) void k_pack(
        const int* __restrict__ masks, uchar4* __restrict__ packed,
        float* __restrict__ cnt, float* __restrict__ sumd,
        float* __restrict__ sumd2) {
    int i = blockIdx.x * blockDim.x + threadIdx.x;   // vec4 pixel index, exact cover
    if (blockIdx.x == 0) {
        int t = threadIdx.x;
        if (t < 8) cnt[t] = 0.f;
        else if (t < 136) sumd[t - 8] = 0.f;
        else if (t < 264) sumd2[t - 136] = 0.f;
    }
    int4 mv[8];
#pragma unroll
    for (int m = 0; m < 8; m++)
        mv[m] = ((const int4*)(masks + (size_t)m * HWPIX))[i];
    __builtin_amdgcn_sched_barrier(0);
    unsigned b0 = 0, b1 = 0, b2 = 0, b3 = 0;
#pragma unroll
    for (int m = 0; m < 8; m++) {
        b0 |= (unsigned)(mv[m].x & 1) << m;
        b1 |= (unsigned)(mv[m].y & 1) << m;
        b2 |= (unsigned)(mv[m].z & 1) << m;
        b3 |= (unsigned)(mv[m].w & 1) << m;
    }
    packed[i] = make_uchar4((unsigned char)b0, (unsigned char)b1,
                            (unsigned char)b2, (unsigned char)b3);
}

// ---------------------------------------------------------------------------
// K2: per-patch coverage counts (all 8 masks) + total count per mask
__global__ void k_cov(const unsigned char* __restrict__ packed,
                      float* __restrict__ cov, float* __restrict__ cnt) {
    int patch = blockIdx.x;            // 0..2303
    int pi = patch / HVIS, pj = patch - pi * HVIS;
    int t = threadIdx.x;               // 256
    float c[8] = {0, 0, 0, 0, 0, 0, 0, 0};
    for (int p = t; p < PATCH * PATCH; p += 256) {
        int r = p / PATCH, q = p - r * PATCH;
        unsigned pb = packed[(pi * PATCH + r) * WWp + pj * PATCH + q];
#pragma unroll
        for (int m = 0; m < 8; m++) c[m] += (float)((pb >> m) & 1u);
    }
    __shared__ float red[8][256];
#pragma unroll
    for (int m = 0; m < 8; m++) red[m][t] = c[m];
    __syncthreads();
    for (int o = 128; o; o >>= 1) {
        if (t < o) {
#pragma unroll
            for (int m = 0; m < 8; m++) red[m][t] += red[m][t + o];
        }
        __syncthreads();
    }
    if (t < 8) {
        cov[t * NPROB + patch] = red[t][0];
        atomicAdd(&cnt[t], red[t][0]);
    }
}

// ---------------------------------------------------------------------------
// K3: scores[b,n] = tokens[b,n,:] . gate  (one wave per row, 8 pinned loads)
__global__ __launch_bounds__(256, 4) void k_scores(
        const float* __restrict__ tokens, const float* __restrict__ gate,
        float* __restrict__ scores) {
    int row = blockIdx.x * 4 + (threadIdx.x >> 6);   // 4 waves/block
    int lane = threadIdx.x & 63;
    const float4* tp = (const float4*)(tokens + (size_t)row * DDIM);
    const float4* gp = (const float4*)gate;
    float4 tv[4], gv[4];
#pragma unroll
    for (int i = 0; i < 4; i++) {
        tv[i] = tp[lane + i * 64];
        gv[i] = gp[lane + i * 64];
    }
    __builtin_amdgcn_sched_barrier(0);
    float s = 0.f;
#pragma unroll
    for (int i = 0; i < 4; i++)
        s += tv[i].x * gv[i].x + tv[i].y * gv[i].y +
             tv[i].z * gv[i].z + tv[i].w * gv[i].w;
#pragma unroll
    for (int o = 32; o; o >>= 1) s += __shfl_down(s, o, 64);
    if (lane == 0) scores[row] = s;
}

// ---------------------------------------------------------------------------
// K4: per mask: soft2d = sigmoid(50*(cov/784-0.3)), log_soft, centroid cx/cy
__global__ void k_soft(const float* __restrict__ cov, float* __restrict__ soft,
                       float* __restrict__ lsoft, float* __restrict__ cent) {
    int m = blockIdx.x, t = threadIdx.x;
    float psum = 0.f, psx = 0.f, psy = 0.f;
#pragma unroll
    for (int i = 0; i < 9; i++) {               // 2304 = 9*256 exactly
        int n = t + i * 256;
        float c = cov[m * NPROB + n] * (1.0f / 784.0f);
        float s = 1.0f / (1.0f + expf(-50.0f * (c - 0.3f)));
        soft[m * NPROB + n] = s;
        lsoft[m * NPROB + n] = logf(fmaxf(s, 1e-8f));
        int row = n / HVIS, col = n - row * HVIS;
        psum += s;
        psx += s * (float)col;
        psy += s * (float)row;
    }
    __shared__ float r0[256], r1[256], r2[256];
    r0[t] = psum; r1[t] = psx; r2[t] = psy;
    __syncthreads();
    for (int o = 128; o; o >>= 1) {
        if (t < o) { r0[t] += r0[t + o]; r1[t] += r1[t + o]; r2[t] += r2[t + o]; }
        __syncthreads();
    }
    if (t == 0) {
        float ss = r0[0] + 1e-8f;
        float cx = r1[0] / (ss * (float)HVIS);
        float cy = r2[0] / (ss * (float)HVIS);
        cent[m * 4 + 0] = cx;
        cent[m * 4 + 1] = cy;
        cent[m * 4 + 2] = cx * (float)(WWp - 1);
        cent[m * 4 + 3] = cy * (float)(HH - 1);
    }
}

// ---------------------------------------------------------------------------
// K5 (v4): depth sum / sum^2 per (mask, b). KPT=4, lane-contiguous, and the
// 8 loads (4 float4 + 4 uchar4) pinned ABOVE compute via sched_barrier(0) so
// they are all in flight together. 441 blocks * 256 * 4 = HWPIX/4 exactly.
constexpr int KPT = 4;
__global__ __launch_bounds__(256, 4) void k_depthstats(
        const float* __restrict__ depth, const uchar4* __restrict__ packed,
        float* __restrict__ sumd, float* __restrict__ sumd2) {
    int b = blockIdx.y;
    int t = threadIdx.x;
    int base4 = blockIdx.x * (256 * KPT);
    const float4* dp4 = (const float4*)(depth + (size_t)b * HWPIX);

    float4 dv[KPT];
    uchar4 pv[KPT];
#pragma unroll
    for (int k = 0; k < KPT; k++) {
        int idx = base4 + k * 256 + t;
        dv[k] = dp4[idx];
        pv[k] = packed[idx];
    }
    __builtin_amdgcn_sched_barrier(0);

    float acc[8] = {0, 0, 0, 0, 0, 0, 0, 0};
    float acc2[8] = {0, 0, 0, 0, 0, 0, 0, 0};
#pragma unroll
    for (int k = 0; k < KPT; k++) {
        float dd[4] = {dv[k].x, dv[k].y, dv[k].z, dv[k].w};
        unsigned bb[4] = {pv[k].x, pv[k].y, pv[k].z, pv[k].w};
#pragma unroll
        for (int j = 0; j < 4; j++) {
            float d = dd[j];
            float sq = d * d;
            unsigned byte = bb[j];
#pragma unroll
            for (int m = 0; m < 8; m++) {
                float f = (float)((byte >> m) & 1u);
                acc[m] = fmaf(f, d, acc[m]);
                acc2[m] = fmaf(f, sq, acc2[m]);
            }
        }
    }
    // wave reduce 16 values
#pragma unroll
    for (int o = 32; o; o >>= 1) {
#pragma unroll
        for (int m = 0; m < 8; m++) {
            acc[m] += __shfl_down(acc[m], o, 64);
            acc2[m] += __shfl_down(acc2[m], o, 64);
        }
    }
    __shared__ float red[2][8][4];
    int wid = threadIdx.x >> 6, lane = threadIdx.x & 63;
    if (lane == 0) {
#pragma unroll
        for (int m = 0; m < 8; m++) {
            red[0][m][wid] = acc[m];
            red[1][m][wid] = acc2[m];
        }
    }
    __syncthreads();
    if (threadIdx.x < 16) {
        int s = threadIdx.x >> 3, m = threadIdx.x & 7;
        float v = red[s][m][0] + red[s][m][1] + red[s][m][2] + red[s][m][3];
        atomicAdd((s ? sumd2 : sumd) + m * BN + b, v);
    }
}

// ---------------------------------------------------------------------------
// K6: rays — bilinear depth (border) + bilinear soft2d (zeros) -> profile
__global__ void k_rays(const float* __restrict__ depth, const float* __restrict__ soft,
                       const float* __restrict__ cent, float* __restrict__ prof) {
    int m = blockIdx.x, b = blockIdx.y, t = threadIdx.x;
    __shared__ float s_sw[NRAY * NSMP], s_d[NRAY * NSMP];
    float cxp = cent[m * 4 + 2], cyp = cent[m * 4 + 3];
    if (t < NRAY * NSMP) {
        int r = t / NSMP, s = t - r * NSMP;
        float ang = (float)r * (6.28318530717958647692f / (float)NRAY);
        float tv = (float)s * (604.8f / (float)(NSMP - 1));
        float xs = fmaf(cosf(ang), tv, cxp);
        float ys = fmaf(sinf(ang), tv, cyp);
        // --- bilinear with border clamp on depth[b]
        float x = fminf(fmaxf(xs, 0.0f), (float)(WWp - 1));
        float y = fminf(fmaxf(ys, 0.0f), (float)(HH - 1));
        float x0f = floorf(x), y0f = floorf(y);
        float wx = x - x0f, wy = y - y0f;
        int x0 = (int)x0f, y0 = (int)y0f;
        int x1 = min(x0 + 1, WWp - 1), y1 = min(y0 + 1, HH - 1);
        const float* dpb = depth + (size_t)b * HWPIX;
        float v00 = dpb[y0 * WWp + x0], v01 = dpb[y0 * WWp + x1];
        float v10 = dpb[y1 * WWp + x0], v11 = dpb[y1 * WWp + x1];
        float ds = v00 * (1 - wx) * (1 - wy) + v01 * wx * (1 - wy) +
                   v10 * (1 - wx) * wy + v11 * wx * wy;
        // --- bilinear with zero padding on soft2d (48x48)
        const float* sp = soft + m * NPROB;
        float xp = xs * ((float)(HVIS - 1) / (float)(WWp - 1));
        float yp = ys * ((float)(HVIS - 1) / (float)(HH - 1));
        float xp0 = floorf(xp), yp0 = floorf(yp);
        float ux = xp - xp0, uy = yp - yp0;
        int a0 = (int)xp0, c0 = (int)yp0;
        float sw = 0.f;
        int xx[2] = {a0, a0 + 1};
        int yy[2] = {c0, c0 + 1};
        float wxt[2] = {1.0f - ux, ux};
        float wyt[2] = {1.0f - uy, uy};
#pragma unroll
        for (int ii = 0; ii < 2; ii++) {
#pragma unroll
            for (int jj = 0; jj < 2; jj++) {
                int yv = yy[ii], xv = xx[jj];
                bool valid = (xv >= 0) && (xv < HVIS) && (yv >= 0) && (yv < HVIS);
                float vv = sp[min(max(yv, 0), HVIS - 1) * HVIS + min(max(xv, 0), HVIS - 1)];
                sw += valid ? vv * wyt[ii] * wxt[jj] : 0.0f;
            }
        }
        sw = fmaxf(sw, 1e-6f);
        s_sw[t] = sw;
        s_d[t] = ds;
    }
    __syncthreads();
    if (t < NRAY) {
        float wsum = 0.f, dot = 0.f;
#pragma unroll
        for (int s = 0; s < NSMP; s++) {
            float w = s_sw[t * NSMP + s];
            wsum += w;
            dot += s_d[t * NSMP + s] * w;
        }
        prof[(m * BN + b) * NRAY + t] = dot / wsum;
    }
}

// ---------------------------------------------------------------------------
// K7: per (m,b) softmax max + sumexp over scores+log_soft
__global__ void k_wred(const float* __restrict__ scores, const float* __restrict__ lsoft,
                       float* __restrict__ smax, float* __restrict__ ssum) {
    int mb = blockIdx.x;
    int m = mb >> 4, b = mb & 15;
    int t = threadIdx.x;
    float v[9];
    float pm = -1e30f;
#pragma unroll
    for (int i = 0; i < 9; i++) {
        int n = t + i * 256;
        float x = scores[b * NTOK + n] + lsoft[m * NTOK + n];
        v[i] = x;
        pm = fmaxf(pm, x);
    }
    __shared__ float r[256];
    r[t] = pm;
    __syncthreads();
    for (int o = 128; o; o >>= 1) {
        if (t < o) r[t] = fmaxf(r[t], r[t + o]);
        __syncthreads();
    }
    float mx = r[0];
    __syncthreads();
    float ps = 0.f;
#pragma unroll
    for (int i = 0; i < 9; i++) ps += expf(v[i] - mx);
    r[t] = ps;
    __syncthreads();
    for (int o = 128; o; o >>= 1) {
        if (t < o) r[t] += r[t + o];
        __syncthreads();
    }
    if (t == 0) { smax[mb] = mx; ssum[mb] = r[0]; }
}

// ---------------------------------------------------------------------------
// K8 (v3): rgb[m,b,:] = sum_n w[m,b,n] * tokens[b,n,:] (all 8 masks per pass)
// 9 explicit batches of 8 pinned float4 loads; weights transposed in LDS
// ([k][m]) so per-token weights come as 2x ds_read_b128 (broadcast).
__global__ __launch_bounds__(256, 2) void k_rgb(
        const float* __restrict__ tokens, const float* __restrict__ scores,
        const float* __restrict__ lsoft, const float* __restrict__ smax,
        const float* __restrict__ ssum, float* __restrict__ rgb) {
    constexpr int CHUNK = 72;   // 2304 / 72 = 32 chunks
    int b = blockIdx.x, chunk = blockIdx.y, t = threadIdx.x;
    int n0 = chunk * CHUNK;
    __shared__ float wl[CHUNK][8];   // [k][m]
    for (int i = t; i < CHUNK * 8; i += 256) {
        int k = i >> 3, m = i & 7;
        int n = n0 + k;
        wl[k][m] = expf(scores[b * NTOK + n] + lsoft[m * NTOK + n] - smax[m * BN + b]) /
                   ssum[m * BN + b];
    }
    __syncthreads();
    float acc[8][4] = {};
    const float4* tp = (const float4*)(tokens + ((size_t)(b * NTOK + n0)) * DDIM);
    for (int c = 0; c < CHUNK / 8; c++) {        // 9 batches
        float4 tk[8];
#pragma unroll
        for (int j = 0; j < 8; j++)
            tk[j] = tp[(size_t)(c * 8 + j) * 256 + t];
        __builtin_amdgcn_sched_barrier(0);
#pragma unroll
        for (int j = 0; j < 8; j++) {
            int k = c * 8 + j;
            const float4* wp = (const float4*)&wl[k][0];
            float4 w0 = wp[0], w1 = wp[1];
            float wm[8] = {w0.x, w0.y, w0.z, w0.w, w1.x, w1.y, w1.z, w1.w};
#pragma unroll
            for (int m = 0; m < 8; m++) {
                float w = wm[m];
                acc[m][0] = fmaf(w, tk[j].x, acc[m][0]);
                acc[m][1] = fmaf(w, tk[j].y, acc[m][1]);
                acc[m][2] = fmaf(w, tk[j].z, acc[m][2]);
                acc[m][3] = fmaf(w, tk[j].w, acc[m][3]);
            }
        }
    }
    int d0 = t * 4;
#pragma unroll
    for (int m = 0; m < 8; m++) {
#pragma unroll
        for (int j = 0; j < 4; j++)
            atomicAdd(&rgb[((size_t)(m * BN + b)) * DDIM + d0 + j], acc[m][j]);
    }
}

// ---------------------------------------------------------------------------
// K9: stats -> h = stats@depth_w + depth_b -> LayerNorm -> dep
__global__ void k_dep(const float* __restrict__ sumd, const float* __restrict__ sumd2,
                      const float* __restrict__ cnt, const float* __restrict__ cent,
                      const float* __restrict__ prof, const float* __restrict__ dw,
                      const float* __restrict__ db, const float* __restrict__ gamma,
                      const float* __restrict__ beta, float* __restrict__ dep) {
    int m = blockIdx.x, b = blockIdx.y, t = threadIdx.x;
    __shared__ float st[28];
    float c = cnt[m];
    if (t < 28) {
        float v;
        if (t == 0) {
            v = sumd[m * BN + b] / fmaxf(c, 1.0f);
        } else if (t == 1) {
            float mean = sumd[m * BN + b] / fmaxf(c, 1.0f);
            float var = (sumd2[m * BN + b] - c * mean * mean) / fmaxf(c - 1.0f, 1.0f);
            var = (c > 1.0f) ? var : 0.0f;
            v = sqrtf(fmaxf(var, 0.0f));
        } else if (t == 2) v = cent[m * 4 + 0];
        else if (t == 3) v = cent[m * 4 + 1];
        else v = prof[(m * BN + b) * NRAY + (t - 4)];
        st[t] = (c > 0.0f) ? v : 0.0f;
    }
    __syncthreads();
    int d0 = t * 4;
    float4 hb = *(const float4*)(db + d0);
    float h0 = hb.x, h1 = hb.y, h2 = hb.z, h3 = hb.w;
#pragma unroll
    for (int k = 0; k < 28; k++) {
        float s = st[k];
        float4 w = *(const float4*)(dw + k * DDIM + d0);
        h0 = fmaf(s, w.x, h0);
        h1 = fmaf(s, w.y, h1);
        h2 = fmaf(s, w.z, h2);
        h3 = fmaf(s, w.w, h3);
    }
    float ps = h0 + h1 + h2 + h3;
    float pq = h0 * h0 + h1 * h1 + h2 * h2 + h3 * h3;
    __shared__ float rs[256], rq[256];
    rs[t] = ps; rq[t] = pq;
    __syncthreads();
    for (int o = 128; o; o >>= 1) {
        if (t < o) { rs[t] += rs[t + o]; rq[t] += rq[t + o]; }
        __syncthreads();
    }
    float mu = rs[0] * (1.0f / (float)DDIM);
    float var = rq[0] * (1.0f / (float)DDIM) - mu * mu;
    float inv = 1.0f / sqrtf(var + 1e-5f);
    float4 g = *(const float4*)(gamma + d0);
    float4 be = *(const float4*)(beta + d0);
    size_t o = ((size_t)(m * BN + b)) * DDIM + d0;
    dep[o + 0] = (h0 - mu) * inv * g.x + be.x;
    dep[o + 1] = (h1 - mu) * inv * g.y + be.y;
    dep[o + 2] = (h2 - mu) * inv * g.z + be.z;
    dep[o + 3] = (h3 - mu) * inv * g.w + be.w;
}

// ---------------------------------------------------------------------------
extern "C" void kernel_launch(void* const* d_in, const int* in_sizes, int n_in,
                              void* d_out, int out_size, void* d_ws, size_t ws_size,
                              hipStream_t stream) {
    const float* tokens = (const float*)d_in[0];
    const float* depth  = (const float*)d_in[1];
    const int*   masks  = (const int*)d_in[2];
    const float* gate   = (const float*)d_in[3];
    const float* dw     = (const float*)d_in[4];
    const float* db     = (const float*)d_in[5];
    const float* gamma  = (const float*)d_in[6];
    const float* beta   = (const float*)d_in[7];
    float* out = (float*)d_out;

    char* ws = (char*)d_ws;
    size_t off = 0;
    auto alloc = [&](size_t bytes) {
        size_t o = off;
        off = (off + bytes + 255) & ~(size_t)255;
        return o;
    };
    unsigned char* packed = (unsigned char*)(ws + alloc(HWPIX));
    float* cov    = (float*)(ws + alloc((size_t)NM * NPROB * 4));
    float* cnt    = (float*)(ws + alloc(NM * 4));
    float* soft   = (float*)(ws + alloc((size_t)NM * NPROB * 4));
    float* lsoft  = (float*)(ws + alloc((size_t)NM * NPROB * 4));
    float* cent   = (float*)(ws + alloc(NM * 4 * 4));
    float* sumd   = (float*)(ws + alloc(NM * BN * 4));
    float* sumd2  = (float*)(ws + alloc(NM * BN * 4));
    float* scores = (float*)(ws + alloc((size_t)BN * NTOK * 4));
    float* smax   = (float*)(ws + alloc(NM * BN * 4));
    float* ssum   = (float*)(ws + alloc(NM * BN * 4));
    float* prof   = (float*)(ws + alloc((size_t)NM * BN * NRAY * 4));

    // rgb half of out must be zero before k_rgb's atomics (out is 0xAA-poisoned)
    hipMemsetAsync(out, 0, (size_t)NM * BN * DDIM * 4, stream);

    k_pack<<<HWPIX / 4 / 256, 256, 0, stream>>>(masks, (uchar4*)packed,
                                                cnt, sumd, sumd2);
    k_cov<<<NPROB, 256, 0, stream>>>(packed, cov, cnt);
    k_scores<<<BN * NTOK / 4, 256, 0, stream>>>(tokens, gate, scores);
    k_soft<<<NM, 256, 0, stream>>>(cov, soft, lsoft, cent);
    k_depthstats<<<dim3(HWPIX / 4 / (256 * KPT), BN), 256, 0, stream>>>(
        depth, (const uchar4*)packed, sumd, sumd2);
    k_rays<<<dim3(NM, BN), 512, 0, stream>>>(depth, soft, cent, prof);
    k_wred<<<NM * BN, 256, 0, stream>>>(scores, lsoft, smax, ssum);
    k_rgb<<<dim3(BN, NTOK / 72), 256, 0, stream>>>(tokens, scores, lsoft, smax, ssum, out);
    k_dep<<<dim3(NM, BN), 256, 0, stream>>>(sumd, sumd2, cnt, cent, prof, dw, db,
                                            gamma, beta,
                                            out + (size_t)NM * BN * DDIM);
}

// Round 10
// 507.804 us; speedup vs baseline: 1.2230x; 1.2230x over previous
//
#include <hip/hip_runtime.h>
#include <math.h>

// Problem constants (shapes fixed by the reference).
constexpr int BN   = 16;        // batch
constexpr int NTOK = 2304;      // tokens
constexpr int DDIM = 1024;      // token dim
constexpr int HH   = 1344;
constexpr int WWp  = 1344;
constexpr int HWPIX = HH * WWp; // 1806336
constexpr int NM   = 8;         // masks
constexpr int HVIS = 48;
constexpr int PATCH = 28;       // 1344/48
constexpr int NRAY = 24;
constexpr int NSMP = 20;
constexpr int NPROB = HVIS * HVIS; // 2304 patches (== NTOK coincidentally)

// ---------------------------------------------------------------------------
// K1: pack 8 int32 mask planes into one byte per pixel (bit m = mask m).
// Also zero-inits cnt/sumd/sumd2 (block 0) to save memset dispatches.
__global__ __launch_bounds__(256, 4) void k_pack(
        const int* __restrict__ masks, uchar4* __restrict__ packed,
        float* __restrict__ cnt, float* __restrict__ sumd,
        float* __restrict__ sumd2) {
    int i = blockIdx.x * blockDim.x + threadIdx.x;   // vec4 pixel index, exact cover
    if (blockIdx.x == 0) {
        int t = threadIdx.x;
        if (t < 8) cnt[t] = 0.f;
        else if (t < 136) sumd[t - 8] = 0.f;
        else if (t < 264) sumd2[t - 136] = 0.f;
    }
    int4 mv[8];
#pragma unroll
    for (int m = 0; m < 8; m++)
        mv[m] = ((const int4*)(masks + (size_t)m * HWPIX))[i];
    __builtin_amdgcn_sched_barrier(0);
    unsigned b0 = 0, b1 = 0, b2 = 0, b3 = 0;
#pragma unroll
    for (int m = 0; m < 8; m++) {
        b0 |= (unsigned)(mv[m].x & 1) << m;
        b1 |= (unsigned)(mv[m].y & 1) << m;
        b2 |= (unsigned)(mv[m].z & 1) << m;
        b3 |= (unsigned)(mv[m].w & 1) << m;
    }
    packed[i] = make_uchar4((unsigned char)b0, (unsigned char)b1,
                            (unsigned char)b2, (unsigned char)b3);
}

// ---------------------------------------------------------------------------
// K2: per-patch coverage counts (all 8 masks) + total count per mask
__global__ void k_cov(const unsigned char* __restrict__ packed,
                      float* __restrict__ cov, float* __restrict__ cnt) {
    int patch = blockIdx.x;            // 0..2303
    int pi = patch / HVIS, pj = patch - pi * HVIS;
    int t = threadIdx.x;               // 256
    float c[8] = {0, 0, 0, 0, 0, 0, 0, 0};
    for (int p = t; p < PATCH * PATCH; p += 256) {
        int r = p / PATCH, q = p - r * PATCH;
        unsigned pb = packed[(pi * PATCH + r) * WWp + pj * PATCH + q];
#pragma unroll
        for (int m = 0; m < 8; m++) c[m] += (float)((pb >> m) & 1u);
    }
    __shared__ float red[8][256];
#pragma unroll
    for (int m = 0; m < 8; m++) red[m][t] = c[m];
    __syncthreads();
    for (int o = 128; o; o >>= 1) {
        if (t < o) {
#pragma unroll
            for (int m = 0; m < 8; m++) red[m][t] += red[m][t + o];
        }
        __syncthreads();
    }
    if (t < 8) {
        cov[t * NPROB + patch] = red[t][0];
        atomicAdd(&cnt[t], red[t][0]);
    }
}

// ---------------------------------------------------------------------------
// K3 (v2): scores[b,n] = tokens[b,n,:] . gate
// 4 rows per WAVE (16 token float4 loads + 4 gate loads pinned together),
// cutting total waves 36864 -> 9216. Grid: 36864/16 = 2304 blocks.
__global__ __launch_bounds__(256, 2) void k_scores(
        const float* __restrict__ tokens, const float* __restrict__ gate,
        float* __restrict__ scores) {
    int wid = threadIdx.x >> 6, lane = threadIdx.x & 63;
    int row0 = blockIdx.x * 16 + wid * 4;
    const float4* gp = (const float4*)gate;
    float4 gv[4];
#pragma unroll
    for (int c = 0; c < 4; c++) gv[c] = gp[lane + c * 64];
    float4 tv[4][4];
#pragma unroll
    for (int r = 0; r < 4; r++) {
        const float4* tp = (const float4*)(tokens + (size_t)(row0 + r) * DDIM);
#pragma unroll
        for (int c = 0; c < 4; c++) tv[r][c] = tp[lane + c * 64];
    }
    __builtin_amdgcn_sched_barrier(0);
    float s[4];
#pragma unroll
    for (int r = 0; r < 4; r++) {
        float a = 0.f;
#pragma unroll
        for (int c = 0; c < 4; c++)
            a += tv[r][c].x * gv[c].x + tv[r][c].y * gv[c].y +
                 tv[r][c].z * gv[c].z + tv[r][c].w * gv[c].w;
        s[r] = a;
    }
#pragma unroll
    for (int o = 32; o; o >>= 1) {
#pragma unroll
        for (int r = 0; r < 4; r++) s[r] += __shfl_down(s[r], o, 64);
    }
    if (lane == 0) {
#pragma unroll
        for (int r = 0; r < 4; r++) scores[row0 + r] = s[r];
    }
}

// ---------------------------------------------------------------------------
// K4: per mask: soft2d = sigmoid(50*(cov/784-0.3)), log_soft, centroid cx/cy
__global__ void k_soft(const float* __restrict__ cov, float* __restrict__ soft,
                       float* __restrict__ lsoft, float* __restrict__ cent) {
    int m = blockIdx.x, t = threadIdx.x;
    float psum = 0.f, psx = 0.f, psy = 0.f;
#pragma unroll
    for (int i = 0; i < 9; i++) {               // 2304 = 9*256 exactly
        int n = t + i * 256;
        float c = cov[m * NPROB + n] * (1.0f / 784.0f);
        float s = 1.0f / (1.0f + expf(-50.0f * (c - 0.3f)));
        soft[m * NPROB + n] = s;
        lsoft[m * NPROB + n] = logf(fmaxf(s, 1e-8f));
        int row = n / HVIS, col = n - row * HVIS;
        psum += s;
        psx += s * (float)col;
        psy += s * (float)row;
    }
    __shared__ float r0[256], r1[256], r2[256];
    r0[t] = psum; r1[t] = psx; r2[t] = psy;
    __syncthreads();
    for (int o = 128; o; o >>= 1) {
        if (t < o) { r0[t] += r0[t + o]; r1[t] += r1[t + o]; r2[t] += r2[t + o]; }
        __syncthreads();
    }
    if (t == 0) {
        float ss = r0[0] + 1e-8f;
        float cx = r1[0] / (ss * (float)HVIS);
        float cy = r2[0] / (ss * (float)HVIS);
        cent[m * 4 + 0] = cx;
        cent[m * 4 + 1] = cy;
        cent[m * 4 + 2] = cx * (float)(WWp - 1);
        cent[m * 4 + 3] = cy * (float)(HH - 1);
    }
}

// ---------------------------------------------------------------------------
// K5 (v5): depth sum / sum^2 per (mask, b). KPT=14 lane-contiguous (v3 style,
// which beat all variants) -> waves halve vs KPT=7. 126 blocks * 256 * 14
// = 451584 = HWPIX/4 exactly. launch_bounds(256,2) permits ~94 VGPRs.
constexpr int KPT = 14;
__global__ __launch_bounds__(256, 2) void k_depthstats(
        const float* __restrict__ depth, const uchar4* __restrict__ packed,
        float* __restrict__ sumd, float* __restrict__ sumd2) {
    int b = blockIdx.y;
    int t = threadIdx.x;
    int base4 = blockIdx.x * (256 * KPT);
    const float4* dp4 = (const float4*)(depth + (size_t)b * HWPIX);

    float4 dv[KPT];
    uchar4 pv[KPT];
#pragma unroll
    for (int k = 0; k < KPT; k++) {
        int idx = base4 + k * 256 + t;
        dv[k] = dp4[idx];
        pv[k] = packed[idx];
    }

    float acc[8] = {0, 0, 0, 0, 0, 0, 0, 0};
    float acc2[8] = {0, 0, 0, 0, 0, 0, 0, 0};
#pragma unroll
    for (int k = 0; k < KPT; k++) {
        float dd[4] = {dv[k].x, dv[k].y, dv[k].z, dv[k].w};
        unsigned bb[4] = {pv[k].x, pv[k].y, pv[k].z, pv[k].w};
#pragma unroll
        for (int j = 0; j < 4; j++) {
            float d = dd[j];
            float sq = d * d;
            unsigned byte = bb[j];
#pragma unroll
            for (int m = 0; m < 8; m++) {
                float f = (float)((byte >> m) & 1u);
                acc[m] = fmaf(f, d, acc[m]);
                acc2[m] = fmaf(f, sq, acc2[m]);
            }
        }
    }
    // wave reduce 16 values
#pragma unroll
    for (int o = 32; o; o >>= 1) {
#pragma unroll
        for (int m = 0; m < 8; m++) {
            acc[m] += __shfl_down(acc[m], o, 64);
            acc2[m] += __shfl_down(acc2[m], o, 64);
        }
    }
    __shared__ float red[2][8][4];
    int wid = threadIdx.x >> 6, lane = threadIdx.x & 63;
    if (lane == 0) {
#pragma unroll
        for (int m = 0; m < 8; m++) {
            red[0][m][wid] = acc[m];
            red[1][m][wid] = acc2[m];
        }
    }
    __syncthreads();
    if (threadIdx.x < 16) {
        int s = threadIdx.x >> 3, m = threadIdx.x & 7;
        float v = red[s][m][0] + red[s][m][1] + red[s][m][2] + red[s][m][3];
        atomicAdd((s ? sumd2 : sumd) + m * BN + b, v);
    }
}

// ---------------------------------------------------------------------------
// K6: rays — bilinear depth (border) + bilinear soft2d (zeros) -> profile
__global__ void k_rays(const float* __restrict__ depth, const float* __restrict__ soft,
                       const float* __restrict__ cent, float* __restrict__ prof) {
    int m = blockIdx.x, b = blockIdx.y, t = threadIdx.x;
    __shared__ float s_sw[NRAY * NSMP], s_d[NRAY * NSMP];
    float cxp = cent[m * 4 + 2], cyp = cent[m * 4 + 3];
    if (t < NRAY * NSMP) {
        int r = t / NSMP, s = t - r * NSMP;
        float ang = (float)r * (6.28318530717958647692f / (float)NRAY);
        float tv = (float)s * (604.8f / (float)(NSMP - 1));
        float xs = fmaf(cosf(ang), tv, cxp);
        float ys = fmaf(sinf(ang), tv, cyp);
        // --- bilinear with border clamp on depth[b]
        float x = fminf(fmaxf(xs, 0.0f), (float)(WWp - 1));
        float y = fminf(fmaxf(ys, 0.0f), (float)(HH - 1));
        float x0f = floorf(x), y0f = floorf(y);
        float wx = x - x0f, wy = y - y0f;
        int x0 = (int)x0f, y0 = (int)y0f;
        int x1 = min(x0 + 1, WWp - 1), y1 = min(y0 + 1, HH - 1);
        const float* dpb = depth + (size_t)b * HWPIX;
        float v00 = dpb[y0 * WWp + x0], v01 = dpb[y0 * WWp + x1];
        float v10 = dpb[y1 * WWp + x0], v11 = dpb[y1 * WWp + x1];
        float ds = v00 * (1 - wx) * (1 - wy) + v01 * wx * (1 - wy) +
                   v10 * (1 - wx) * wy + v11 * wx * wy;
        // --- bilinear with zero padding on soft2d (48x48)
        const float* sp = soft + m * NPROB;
        float xp = xs * ((float)(HVIS - 1) / (float)(WWp - 1));
        float yp = ys * ((float)(HVIS - 1) / (float)(HH - 1));
        float xp0 = floorf(xp), yp0 = floorf(yp);
        float ux = xp - xp0, uy = yp - yp0;
        int a0 = (int)xp0, c0 = (int)yp0;
        float sw = 0.f;
        int xx[2] = {a0, a0 + 1};
        int yy[2] = {c0, c0 + 1};
        float wxt[2] = {1.0f - ux, ux};
        float wyt[2] = {1.0f - uy, uy};
#pragma unroll
        for (int ii = 0; ii < 2; ii++) {
#pragma unroll
            for (int jj = 0; jj < 2; jj++) {
                int yv = yy[ii], xv = xx[jj];
                bool valid = (xv >= 0) && (xv < HVIS) && (yv >= 0) && (yv < HVIS);
                float vv = sp[min(max(yv, 0), HVIS - 1) * HVIS + min(max(xv, 0), HVIS - 1)];
                sw += valid ? vv * wyt[ii] * wxt[jj] : 0.0f;
            }
        }
        sw = fmaxf(sw, 1e-6f);
        s_sw[t] = sw;
        s_d[t] = ds;
    }
    __syncthreads();
    if (t < NRAY) {
        float wsum = 0.f, dot = 0.f;
#pragma unroll
        for (int s = 0; s < NSMP; s++) {
            float w = s_sw[t * NSMP + s];
            wsum += w;
            dot += s_d[t * NSMP + s] * w;
        }
        prof[(m * BN + b) * NRAY + t] = dot / wsum;
    }
}

// ---------------------------------------------------------------------------
// K7: per (m,b) softmax max + sumexp over scores+log_soft
__global__ void k_wred(const float* __restrict__ scores, const float* __restrict__ lsoft,
                       float* __restrict__ smax, float* __restrict__ ssum) {
    int mb = blockIdx.x;
    int m = mb >> 4, b = mb & 15;
    int t = threadIdx.x;
    float v[9];
    float pm = -1e30f;
#pragma unroll
    for (int i = 0; i < 9; i++) {
        int n = t + i * 256;
        float x = scores[b * NTOK + n] + lsoft[m * NTOK + n];
        v[i] = x;
        pm = fmaxf(pm, x);
    }
    __shared__ float r[256];
    r[t] = pm;
    __syncthreads();
    for (int o = 128; o; o >>= 1) {
        if (t < o) r[t] = fmaxf(r[t], r[t + o]);
        __syncthreads();
    }
    float mx = r[0];
    __syncthreads();
    float ps = 0.f;
#pragma unroll
    for (int i = 0; i < 9; i++) ps += expf(v[i] - mx);
    r[t] = ps;
    __syncthreads();
    for (int o = 128; o; o >>= 1) {
        if (t < o) r[t] += r[t + o];
        __syncthreads();
    }
    if (t == 0) { smax[mb] = mx; ssum[mb] = r[0]; }
}

// ---------------------------------------------------------------------------
// K8: rgb[m,b,:] = sum_n w[m,b,n] * tokens[b,n,:] (all 8 masks per pass)
// 9 explicit batches of 8 pinned float4 loads; weights transposed in LDS.
__global__ __launch_bounds__(256, 2) void k_rgb(
        const float* __restrict__ tokens, const float* __restrict__ scores,
        const float* __restrict__ lsoft, const float* __restrict__ smax,
        const float* __restrict__ ssum, float* __restrict__ rgb) {
    constexpr int CHUNK = 72;   // 2304 / 72 = 32 chunks
    int b = blockIdx.x, chunk = blockIdx.y, t = threadIdx.x;
    int n0 = chunk * CHUNK;
    __shared__ float wl[CHUNK][8];   // [k][m]
    for (int i = t; i < CHUNK * 8; i += 256) {
        int k = i >> 3, m = i & 7;
        int n = n0 + k;
        wl[k][m] = expf(scores[b * NTOK + n] + lsoft[m * NTOK + n] - smax[m * BN + b]) /
                   ssum[m * BN + b];
    }
    __syncthreads();
    float acc[8][4] = {};
    const float4* tp = (const float4*)(tokens + ((size_t)(b * NTOK + n0)) * DDIM);
    for (int c = 0; c < CHUNK / 8; c++) {        // 9 batches
        float4 tk[8];
#pragma unroll
        for (int j = 0; j < 8; j++)
            tk[j] = tp[(size_t)(c * 8 + j) * 256 + t];
        __builtin_amdgcn_sched_barrier(0);
#pragma unroll
        for (int j = 0; j < 8; j++) {
            int k = c * 8 + j;
            const float4* wp = (const float4*)&wl[k][0];
            float4 w0 = wp[0], w1 = wp[1];
            float wm[8] = {w0.x, w0.y, w0.z, w0.w, w1.x, w1.y, w1.z, w1.w};
#pragma unroll
            for (int m = 0; m < 8; m++) {
                float w = wm[m];
                acc[m][0] = fmaf(w, tk[j].x, acc[m][0]);
                acc[m][1] = fmaf(w, tk[j].y, acc[m][1]);
                acc[m][2] = fmaf(w, tk[j].z, acc[m][2]);
                acc[m][3] = fmaf(w, tk[j].w, acc[m][3]);
            }
        }
    }
    int d0 = t * 4;
#pragma unroll
    for (int m = 0; m < 8; m++) {
#pragma unroll
        for (int j = 0; j < 4; j++)
            atomicAdd(&rgb[((size_t)(m * BN + b)) * DDIM + d0 + j], acc[m][j]);
    }
}

// ---------------------------------------------------------------------------
// K9: stats -> h = stats@depth_w + depth_b -> LayerNorm -> dep
__global__ void k_dep(const float* __restrict__ sumd, const float* __restrict__ sumd2,
                      const float* __restrict__ cnt, const float* __restrict__ cent,
                      const float* __restrict__ prof, const float* __restrict__ dw,
                      const float* __restrict__ db, const float* __restrict__ gamma,
                      const float* __restrict__ beta, float* __restrict__ dep) {
    int m = blockIdx.x, b = blockIdx.y, t = threadIdx.x;
    __shared__ float st[28];
    float c = cnt[m];
    if (t < 28) {
        float v;
        if (t == 0) {
            v = sumd[m * BN + b] / fmaxf(c, 1.0f);
        } else if (t == 1) {
            float mean = sumd[m * BN + b] / fmaxf(c, 1.0f);
            float var = (sumd2[m * BN + b] - c * mean * mean) / fmaxf(c - 1.0f, 1.0f);
            var = (c > 1.0f) ? var : 0.0f;
            v = sqrtf(fmaxf(var, 0.0f));
        } else if (t == 2) v = cent[m * 4 + 0];
        else if (t == 3) v = cent[m * 4 + 1];
        else v = prof[(m * BN + b) * NRAY + (t - 4)];
        st[t] = (c > 0.0f) ? v : 0.0f;
    }
    __syncthreads();
    int d0 = t * 4;
    float4 hb = *(const float4*)(db + d0);
    float h0 = hb.x, h1 = hb.y, h2 = hb.z, h3 = hb.w;
#pragma unroll
    for (int k = 0; k < 28; k++) {
        float s = st[k];
        float4 w = *(const float4*)(dw + k * DDIM + d0);
        h0 = fmaf(s, w.x, h0);
        h1 = fmaf(s, w.y, h1);
        h2 = fmaf(s, w.z, h2);
        h3 = fmaf(s, w.w, h3);
    }
    float ps = h0 + h1 + h2 + h3;
    float pq = h0 * h0 + h1 * h1 + h2 * h2 + h3 * h3;
    __shared__ float rs[256], rq[256];
    rs[t] = ps; rq[t] = pq;
    __syncthreads();
    for (int o = 128; o; o >>= 1) {
        if (t < o) { rs[t] += rs[t + o]; rq[t] += rq[t + o]; }
        __syncthreads();
    }
    float mu = rs[0] * (1.0f / (float)DDIM);
    float var = rq[0] * (1.0f / (float)DDIM) - mu * mu;
    float inv = 1.0f / sqrtf(var + 1e-5f);
    float4 g = *(const float4*)(gamma + d0);
    float4 be = *(const float4*)(beta + d0);
    size_t o = ((size_t)(m * BN + b)) * DDIM + d0;
    dep[o + 0] = (h0 - mu) * inv * g.x + be.x;
    dep[o + 1] = (h1 - mu) * inv * g.y + be.y;
    dep[o + 2] = (h2 - mu) * inv * g.z + be.z;
    dep[o + 3] = (h3 - mu) * inv * g.w + be.w;
}

// ---------------------------------------------------------------------------
extern "C" void kernel_launch(void* const* d_in, const int* in_sizes, int n_in,
                              void* d_out, int out_size, void* d_ws, size_t ws_size,
                              hipStream_t stream) {
    const float* tokens = (const float*)d_in[0];
    const float* depth  = (const float*)d_in[1];
    const int*   masks  = (const int*)d_in[2];
    const float* gate   = (const float*)d_in[3];
    const float* dw     = (const float*)d_in[4];
    const float* db     = (const float*)d_in[5];
    const float* gamma  = (const float*)d_in[6];
    const float* beta   = (const float*)d_in[7];
    float* out = (float*)d_out;

    char* ws = (char*)d_ws;
    size_t off = 0;
    auto alloc = [&](size_t bytes) {
        size_t o = off;
        off = (off + bytes + 255) & ~(size_t)255;
        return o;
    };
    unsigned char* packed = (unsigned char*)(ws + alloc(HWPIX));
    float* cov    = (float*)(ws + alloc((size_t)NM * NPROB * 4));
    float* cnt    = (float*)(ws + alloc(NM * 4));
    float* soft   = (float*)(ws + alloc((size_t)NM * NPROB * 4));
    float* lsoft  = (float*)(ws + alloc((size_t)NM * NPROB * 4));
    float* cent   = (float*)(ws + alloc(NM * 4 * 4));
    float* sumd   = (float*)(ws + alloc(NM * BN * 4));
    float* sumd2  = (float*)(ws + alloc(NM * BN * 4));
    float* scores = (float*)(ws + alloc((size_t)BN * NTOK * 4));
    float* smax   = (float*)(ws + alloc(NM * BN * 4));
    float* ssum   = (float*)(ws + alloc(NM * BN * 4));
    float* prof   = (float*)(ws + alloc((size_t)NM * BN * NRAY * 4));

    // rgb half of out must be zero before k_rgb's atomics (out is 0xAA-poisoned)
    hipMemsetAsync(out, 0, (size_t)NM * BN * DDIM * 4, stream);

    k_pack<<<HWPIX / 4 / 256, 256, 0, stream>>>(masks, (uchar4*)packed,
                                                cnt, sumd, sumd2);
    k_cov<<<NPROB, 256, 0, stream>>>(packed, cov, cnt);
    k_scores<<<BN * NTOK / 16, 256, 0, stream>>>(tokens, gate, scores);
    k_soft<<<NM, 256, 0, stream>>>(cov, soft, lsoft, cent);
    k_depthstats<<<dim3(HWPIX / 4 / (256 * KPT), BN), 256, 0, stream>>>(
        depth, (const uchar4*)packed, sumd, sumd2);
    k_rays<<<dim3(NM, BN), 512, 0, stream>>>(depth, soft, cent, prof);
    k_wred<<<NM * BN, 256, 0, stream>>>(scores, lsoft, smax, ssum);
    k_rgb<<<dim3(BN, NTOK / 72), 256, 0, stream>>>(tokens, scores, lsoft, smax, ssum, out);
    k_dep<<<dim3(NM, BN), 256, 0, stream>>>(sumd, sumd2, cnt, cent, prof, dw, db,
                                            gamma, beta,
                                            out + (size_t)NM * BN * DDIM);
}